// Round 2
// baseline (2557.083 us; speedup 1.0000x reference)
//
#include <hip/hip_runtime.h>
#include <float.h>

typedef __attribute__((ext_vector_type(8))) short bf16x8;
typedef __attribute__((ext_vector_type(4))) float f32x4;
typedef unsigned long long u64;
typedef unsigned int u32;
typedef unsigned short u16;

#define NN 32768
#define KK 8192
#define DD 256
#define BM 128
#define BN 128
#define NTILES (KK / BN)   // 64
#define CAP 131072
#define MARGIN 1e-3f

// ---- fast-path ws byte offsets ----
#define WB_ENORM   0
#define WB_XNORM   (WB_ENORM + KK*4)
#define WB_EH      (WB_XNORM + NN*4)
#define WB_EL      (WB_EH + KK*DD*2)
#define WB_PARTIAL (WB_EL + KK*DD*2)
#define WB_ROWBEST (WB_PARTIAL + NN*NTILES*4)
#define WB_LIST    (WB_ROWBEST + NN*8)
#define WB_COUNT   (WB_LIST + CAP*8)
#define WB_LOSS    (WB_COUNT + 4)
#define WB_NEED    ((size_t)(WB_LOSS + 4))

// ---- fallback (round-1) ws float offsets ----
#define CSPLIT 4
#define WSF_ENORM 0
#define WSF_XNORM (KK)
#define WSF_CANDV (KK + NN)
#define WSF_CANDI (KK + NN + NN*CSPLIT)
#define WSF_LOSS  (KK + NN + 2*NN*CSPLIT)

__device__ inline void gload16(const void* g, void* l) {
  __builtin_amdgcn_global_load_lds(
      (const __attribute__((address_space(1))) u32*)g,
      (__attribute__((address_space(3))) u32*)l, 16, 0, 0);
}

__device__ inline u16 bf16_rtne(float f) {
  u32 u = __float_as_uint(f);
  return (u16)((u + 0x7FFFu + ((u >> 16) & 1u)) >> 16);
}

// ---------------- shared: norms ----------------
__global__ __launch_bounds__(256) void vq_norms(const float* __restrict__ x,
                                                const float* __restrict__ emb,
                                                float* __restrict__ enorm,
                                                float* __restrict__ xnorm) {
  int gid = blockIdx.x * blockDim.x + threadIdx.x;
  int wave = gid >> 6, lane = gid & 63;
  const float* src;
  float* dst;
  if (wave < KK) {
    src = emb + (size_t)wave * DD;
    dst = enorm + wave;
  } else {
    int r = wave - KK;
    if (r >= NN) return;
    src = x + (size_t)r * DD;
    dst = xnorm + r;
  }
  float4 v = ((const float4*)src)[lane];
  float s = v.x * v.x + v.y * v.y + v.z * v.z + v.w * v.w;
#pragma unroll
  for (int off = 32; off > 0; off >>= 1) s += __shfl_down(s, off, 64);
  if (lane == 0) *dst = s;
}

// ---------------- fast path ----------------
__global__ __launch_bounds__(256) void vq_cvt(const float* __restrict__ src,
                                              u16* __restrict__ hi,
                                              u16* __restrict__ lo, int n4) {
  int i = blockIdx.x * blockDim.x + threadIdx.x;
  if (i >= n4) return;
  float4 v = ((const float4*)src)[i];
  ushort4 h, l;
  h.x = bf16_rtne(v.x); l.x = bf16_rtne(v.x - __uint_as_float((u32)h.x << 16));
  h.y = bf16_rtne(v.y); l.y = bf16_rtne(v.y - __uint_as_float((u32)h.y << 16));
  h.z = bf16_rtne(v.z); l.z = bf16_rtne(v.z - __uint_as_float((u32)h.z << 16));
  h.w = bf16_rtne(v.w); l.w = bf16_rtne(v.w - __uint_as_float((u32)h.w << 16));
  ((ushort4*)hi)[i] = h;
  ((ushort4*)lo)[i] = l;
}

__global__ __launch_bounds__(256) void vq_mfma(const u16* __restrict__ xh,
                                               const u16* __restrict__ xl,
                                               const u16* __restrict__ eh,
                                               const u16* __restrict__ el,
                                               const float* __restrict__ xnorm,
                                               const float* __restrict__ enorm,
                                               u32* __restrict__ partial) {
  // LDS: [plane][k-group u][row][8 bf16]; frag reads are contiguous 256B per
  // 16-lane group -> uniform 2-way bank aliasing (free); gload_lds dest linear.
  __shared__ u16 lds[4][4][128][8];
  const int tid = threadIdx.x;
  const int lane = tid & 63;
  const int wid = tid >> 6;
  const int wr = wid >> 1, wc = wid & 1;
  const int r0 = blockIdx.x * BM;
  const int c0 = blockIdx.y * BN;

  const u16* plane_src = (wid == 0) ? xh : (wid == 1) ? xl : (wid == 2) ? eh : el;
  const int prow0 = (wid < 2) ? r0 : c0;

  f32x4 acc[4][4];
#pragma unroll
  for (int i = 0; i < 4; ++i)
#pragma unroll
    for (int j = 0; j < 4; ++j) acc[i][j] = (f32x4){0.f, 0.f, 0.f, 0.f};

  const int u_ = lane >> 4;
  const int t_ = lane & 15;

  for (int kc = 0; kc < DD; kc += 32) {
    __syncthreads();
#pragma unroll
    for (int i = 0; i < 8; ++i) {
      const int li = i * 64 + lane;
      const int uu = li >> 7, rr = li & 127;
      gload16(plane_src + ((size_t)(prow0 + rr) * DD + (kc + uu * 8)),
              &lds[wid][uu][rr][0]);
    }
    __syncthreads();
    bf16x8 bh[4], bl[4];
#pragma unroll
    for (int nf = 0; nf < 4; ++nf) {
      const int col = wc * 64 + nf * 16 + t_;
      bh[nf] = *(const bf16x8*)&lds[2][u_][col][0];
      bl[nf] = *(const bf16x8*)&lds[3][u_][col][0];
    }
#pragma unroll
    for (int mf = 0; mf < 4; ++mf) {
      const int rowl = wr * 64 + mf * 16 + t_;
      bf16x8 ah = *(const bf16x8*)&lds[0][u_][rowl][0];
      bf16x8 al = *(const bf16x8*)&lds[1][u_][rowl][0];
#pragma unroll
      for (int nf = 0; nf < 4; ++nf) {
        acc[mf][nf] = __builtin_amdgcn_mfma_f32_16x16x32_bf16(ah, bh[nf], acc[mf][nf], 0, 0, 0);
        acc[mf][nf] = __builtin_amdgcn_mfma_f32_16x16x32_bf16(ah, bl[nf], acc[mf][nf], 0, 0, 0);
        acc[mf][nf] = __builtin_amdgcn_mfma_f32_16x16x32_bf16(al, bh[nf], acc[mf][nf], 0, 0, 0);
      }
    }
  }

  // epilogue: approximate d2, per-(row, tile) min -> ws.partial
#pragma unroll
  for (int mf = 0; mf < 4; ++mf) {
#pragma unroll
    for (int q = 0; q < 4; ++q) {
      const int r = r0 + wr * 64 + mf * 16 + u_ * 4 + q;
      const float xx = xnorm[r];
      float bv = FLT_MAX;
#pragma unroll
      for (int nf = 0; nf < 4; ++nf) {
        const int c = c0 + wc * 64 + nf * 16 + t_;
        float tt = fmaf(-2.f, acc[mf][nf][q], xx);
        float d2 = tt + enorm[c];
        bv = fminf(bv, d2);
      }
#pragma unroll
      for (int off = 1; off < 16; off <<= 1) bv = fminf(bv, __shfl_xor(bv, off, 64));
      if (t_ == 0)
        atomicMin(&partial[(size_t)r * NTILES + blockIdx.y], __float_as_uint(bv));
    }
  }
}

__global__ __launch_bounds__(256) void vq_select(const u32* __restrict__ partial,
                                                 u32* __restrict__ list,
                                                 u32* __restrict__ count) {
  int row = blockIdx.x * blockDim.x + threadIdx.x;
  if (row >= NN) return;
  const u32* p = partial + (size_t)row * NTILES;
  float m = FLT_MAX;
  for (int t = 0; t < NTILES; ++t) m = fminf(m, __uint_as_float(p[t]));
  float thr = m + MARGIN;
  for (int t = 0; t < NTILES; ++t) {
    if (__uint_as_float(p[t]) <= thr) {
      u32 pos = atomicAdd(count, 1u);
      if (pos < CAP) { list[2 * pos] = (u32)row; list[2 * pos + 1] = (u32)t; }
    }
  }
}

__global__ __launch_bounds__(256) void vq_rescore(const float* __restrict__ x,
                                                  const float* __restrict__ emb,
                                                  const float* __restrict__ xnorm,
                                                  const float* __restrict__ enorm,
                                                  const u32* __restrict__ list,
                                                  const u32* __restrict__ count,
                                                  u64* __restrict__ rowbest) {
  const int lane = threadIdx.x & 63;
  const u32 wid0 = (blockIdx.x * blockDim.x + threadIdx.x) >> 6;
  const u32 nw = (gridDim.x * blockDim.x) >> 6;
  u32 cnt = *count;
  if (cnt > CAP) cnt = CAP;
  for (u32 e = wid0; e < cnt; e += nw) {
    const int row = (int)list[2 * e];
    const int tile = (int)list[2 * e + 1];
    const int ca = tile * BN + lane, cb = ca + 64;
    const float* xr = x + (size_t)row * DD;
    const float* e0 = emb + (size_t)ca * DD;
    const float* e1 = emb + (size_t)cb * DD;
    float a0 = 0.f, a1 = 0.f;
    // sequential fmaf chain in ascending d: bit-identical to validated R1 path
#pragma unroll 8
    for (int d = 0; d < DD; d += 4) {
      float4 xv = *(const float4*)(xr + d);
      float4 v0 = *(const float4*)(e0 + d);
      float4 v1 = *(const float4*)(e1 + d);
      a0 = fmaf(xv.x, v0.x, a0); a1 = fmaf(xv.x, v1.x, a1);
      a0 = fmaf(xv.y, v0.y, a0); a1 = fmaf(xv.y, v1.y, a1);
      a0 = fmaf(xv.z, v0.z, a0); a1 = fmaf(xv.z, v1.z, a1);
      a0 = fmaf(xv.w, v0.w, a0); a1 = fmaf(xv.w, v1.w, a1);
    }
    const float xx = xnorm[row];
    float d20 = fmaf(-2.f, a0, xx) + enorm[ca];
    float d21 = fmaf(-2.f, a1, xx) + enorm[cb];
    u64 p0 = ((u64)__float_as_uint(d20) << 32) | (u32)ca;
    u64 p1 = ((u64)__float_as_uint(d21) << 32) | (u32)cb;
    u64 pm = p0 < p1 ? p0 : p1;
#pragma unroll
    for (int off = 1; off < 64; off <<= 1) {
      u64 o = __shfl_xor(pm, off, 64);
      pm = o < pm ? o : pm;
    }
    if (lane == 0) atomicMin(rowbest + row, pm);
  }
}

__global__ __launch_bounds__(256) void vq_gather(const float* __restrict__ x,
                                                 const float* __restrict__ emb,
                                                 const u64* __restrict__ rowbest,
                                                 float* __restrict__ loss_acc,
                                                 float* __restrict__ out) {
  int gid = blockIdx.x * blockDim.x + threadIdx.x;
  int row = gid >> 6, lane = gid & 63;
  if (row >= NN) return;
  int bi = (int)(u32)(rowbest[row] & 0xFFFFFFFFull);
  if (lane == 0) out[(size_t)NN * DD + 2 + row] = (float)bi;

  float4 q = ((const float4*)(emb + (size_t)bi * DD))[lane];
  float4 xv = ((const float4*)(x + (size_t)row * DD))[lane];
  float4 st;
  st.x = xv.x + (q.x - xv.x);
  st.y = xv.y + (q.y - xv.y);
  st.z = xv.z + (q.z - xv.z);
  st.w = xv.w + (q.w - xv.w);
  ((float4*)(out + (size_t)row * DD))[lane] = st;

  float dx = xv.x - q.x, dy = xv.y - q.y, dz = xv.z - q.z, dw = xv.w - q.w;
  float s2 = dx * dx + dy * dy + dz * dz + dw * dw;
#pragma unroll
  for (int off = 32; off > 0; off >>= 1) s2 += __shfl_down(s2, off, 64);
  if (lane == 0) atomicAdd(loss_acc, s2);
}

__global__ void vq_finalize(const float* __restrict__ loss_acc, float* __restrict__ out) {
  float loss = *loss_acc / (float)((size_t)NN * DD);
  out[(size_t)NN * DD] = loss;
  out[(size_t)NN * DD + 1] = loss;
}

// ---------------- fallback path (round-1, validated) ----------------
__global__ __launch_bounds__(256) void fb_argmin(const float* __restrict__ x,
                                                 const float* __restrict__ emb,
                                                 float* __restrict__ ws) {
  const float* enorm = ws + WSF_ENORM;
  const float* xnorm = ws + WSF_XNORM;
  float* candv = ws + WSF_CANDV;
  int* candi = (int*)(ws + WSF_CANDI);

  __shared__ float As[32][BM + 4];
  __shared__ float Bs[32][BN + 4];

  const int tid = threadIdx.x;
  const int tr = tid >> 4, tc = tid & 15;
  const int r0 = blockIdx.x * BM;
  const int split = blockIdx.y;
  const int cbase = split * (KK / CSPLIT);

  float xr[8];
  {
    const float4* p = (const float4*)(xnorm + r0 + tr * 8);
    float4 a = p[0], b = p[1];
    xr[0] = a.x; xr[1] = a.y; xr[2] = a.z; xr[3] = a.w;
    xr[4] = b.x; xr[5] = b.y; xr[6] = b.z; xr[7] = b.w;
  }
  float bestv[8];
  int besti[8];
#pragma unroll
  for (int i = 0; i < 8; i++) { bestv[i] = FLT_MAX; besti[i] = 0; }

  for (int ct = 0; ct < (KK / CSPLIT) / BN; ++ct) {
    const int c0 = cbase + ct * BN;
    float acc[8][8];
#pragma unroll
    for (int i = 0; i < 8; i++)
#pragma unroll
      for (int j = 0; j < 8; j++) acc[i][j] = 0.f;

    for (int kc = 0; kc < DD; kc += 32) {
      __syncthreads();
      {
        const int rrow = tid >> 3, dg = tid & 7;
#pragma unroll
        for (int p = 0; p < 4; ++p) {
          int rw = p * 32 + rrow;
          float4 av = ((const float4*)(x + (size_t)(r0 + rw) * DD + kc))[dg];
          float4 bv = ((const float4*)(emb + (size_t)(c0 + rw) * DD + kc))[dg];
          As[dg * 4 + 0][rw] = av.x; As[dg * 4 + 1][rw] = av.y;
          As[dg * 4 + 2][rw] = av.z; As[dg * 4 + 3][rw] = av.w;
          Bs[dg * 4 + 0][rw] = bv.x; Bs[dg * 4 + 1][rw] = bv.y;
          Bs[dg * 4 + 2][rw] = bv.z; Bs[dg * 4 + 3][rw] = bv.w;
        }
      }
      __syncthreads();
#pragma unroll 4
      for (int kk = 0; kk < 32; ++kk) {
        float4 a0 = *(const float4*)&As[kk][tr * 8];
        float4 a1 = *(const float4*)&As[kk][tr * 8 + 4];
        float4 b0 = *(const float4*)&Bs[kk][tc * 8];
        float4 b1 = *(const float4*)&Bs[kk][tc * 8 + 4];
        float a[8] = {a0.x, a0.y, a0.z, a0.w, a1.x, a1.y, a1.z, a1.w};
        float b[8] = {b0.x, b0.y, b0.z, b0.w, b1.x, b1.y, b1.z, b1.w};
#pragma unroll
        for (int i = 0; i < 8; i++)
#pragma unroll
          for (int j = 0; j < 8; j++) acc[i][j] = fmaf(a[i], b[j], acc[i][j]);
      }
    }
    float en[8];
    {
      const float4* p = (const float4*)(enorm + c0 + tc * 8);
      float4 a = p[0], b = p[1];
      en[0] = a.x; en[1] = a.y; en[2] = a.z; en[3] = a.w;
      en[4] = b.x; en[5] = b.y; en[6] = b.z; en[7] = b.w;
    }
#pragma unroll
    for (int i = 0; i < 8; i++) {
#pragma unroll
      for (int j = 0; j < 8; j++) {
        float t = fmaf(-2.f, acc[i][j], xr[i]);
        float d2 = t + en[j];
        int code = c0 + tc * 8 + j;
        if (d2 < bestv[i]) { bestv[i] = d2; besti[i] = code; }
      }
    }
  }
#pragma unroll
  for (int i = 0; i < 8; i++) {
    float v = bestv[i];
    int bi = besti[i];
#pragma unroll
    for (int off = 1; off < 16; off <<= 1) {
      float v2 = __shfl_xor(v, off, 64);
      int i2 = __shfl_xor(bi, off, 64);
      if (v2 < v || (v2 == v && i2 < bi)) { v = v2; bi = i2; }
    }
    if (tc == 0) {
      int row = r0 + tr * 8 + i;
      candv[row * CSPLIT + split] = v;
      candi[row * CSPLIT + split] = bi;
    }
  }
}

__global__ __launch_bounds__(256) void fb_gather(const float* __restrict__ x,
                                                 const float* __restrict__ emb,
                                                 float* __restrict__ ws,
                                                 float* __restrict__ out) {
  const float* candv = ws + WSF_CANDV;
  const int* candi = (const int*)(ws + WSF_CANDI);
  float* loss_acc = ws + WSF_LOSS;

  int gid = blockIdx.x * blockDim.x + threadIdx.x;
  int row = gid >> 6, lane = gid & 63;
  if (row >= NN) return;

  float bv = candv[row * CSPLIT];
  int bi = candi[row * CSPLIT];
#pragma unroll
  for (int s = 1; s < CSPLIT; s++) {
    float v = candv[row * CSPLIT + s];
    int ii = candi[row * CSPLIT + s];
    if (v < bv || (v == bv && ii < bi)) { bv = v; bi = ii; }
  }
  if (lane == 0) out[(size_t)NN * DD + 2 + row] = (float)bi;

  float4 q = ((const float4*)(emb + (size_t)bi * DD))[lane];
  float4 xv = ((const float4*)(x + (size_t)row * DD))[lane];
  float4 st;
  st.x = xv.x + (q.x - xv.x);
  st.y = xv.y + (q.y - xv.y);
  st.z = xv.z + (q.z - xv.z);
  st.w = xv.w + (q.w - xv.w);
  ((float4*)(out + (size_t)row * DD))[lane] = st;

  float dx = xv.x - q.x, dy = xv.y - q.y, dz = xv.z - q.z, dw = xv.w - q.w;
  float s2 = dx * dx + dy * dy + dz * dz + dw * dw;
#pragma unroll
  for (int off = 32; off > 0; off >>= 1) s2 += __shfl_down(s2, off, 64);
  if (lane == 0) atomicAdd(loss_acc, s2);
}

__global__ void fb_finalize(const float* __restrict__ ws, float* __restrict__ out) {
  float loss = ws[WSF_LOSS] / (float)((size_t)NN * DD);
  out[(size_t)NN * DD] = loss;
  out[(size_t)NN * DD + 1] = loss;
}

// ---------------- launch ----------------
extern "C" void kernel_launch(void* const* d_in, const int* in_sizes, int n_in,
                              void* d_out, int out_size, void* d_ws, size_t ws_size,
                              hipStream_t stream) {
  const float* x = (const float*)d_in[0];
  const float* emb = (const float*)d_in[1];
  float* out = (float*)d_out;
  char* ws = (char*)d_ws;

  if (ws_size >= WB_NEED) {
    // fast path: bf16 hi/lo MFMA + exact rescore
    float* enorm = (float*)(ws + WB_ENORM);
    float* xnorm = (float*)(ws + WB_XNORM);
    u16* eh = (u16*)(ws + WB_EH);
    u16* el = (u16*)(ws + WB_EL);
    u32* partial = (u32*)(ws + WB_PARTIAL);
    u64* rowbest = (u64*)(ws + WB_ROWBEST);
    u32* list = (u32*)(ws + WB_LIST);
    u32* count = (u32*)(ws + WB_COUNT);
    float* loss = (float*)(ws + WB_LOSS);
    // x hi/lo planes live in d_out's quantized region (overwritten by gather later)
    u16* xh = (u16*)out;
    u16* xl = xh + (size_t)NN * DD;

    hipMemsetAsync(ws + WB_PARTIAL, 0x7F, (size_t)NN * NTILES * 4, stream);  // 3.39e38
    hipMemsetAsync(ws + WB_ROWBEST, 0xFF, (size_t)NN * 8, stream);
    hipMemsetAsync(ws + WB_COUNT, 0, 8, stream);  // count + loss

    vq_cvt<<<(KK * DD / 4) / 256, 256, 0, stream>>>(emb, eh, el, KK * DD / 4);
    vq_cvt<<<(NN * DD / 4) / 256, 256, 0, stream>>>(x, xh, xl, NN * DD / 4);
    vq_norms<<<((KK + NN) * 64) / 256, 256, 0, stream>>>(x, emb, enorm, xnorm);
    vq_mfma<<<dim3(NN / BM, KK / BN), 256, 0, stream>>>(xh, xl, eh, el, xnorm, enorm, partial);
    vq_select<<<NN / 256, 256, 0, stream>>>(partial, list, count);
    vq_rescore<<<2048, 256, 0, stream>>>(x, emb, xnorm, enorm, list, count, rowbest);
    vq_gather<<<(NN * 64) / 256, 256, 0, stream>>>(x, emb, rowbest, loss, out);
    vq_finalize<<<1, 1, 0, stream>>>(loss, out);
  } else {
    // fallback: round-1 validated f32 path
    float* wsf = (float*)d_ws;
    hipMemsetAsync(ws + (size_t)WSF_LOSS * 4, 0, 4, stream);
    vq_norms<<<((KK + NN) * 64) / 256, 256, 0, stream>>>(x, emb, wsf + WSF_ENORM, wsf + WSF_XNORM);
    fb_argmin<<<dim3(NN / BM, CSPLIT), 256, 0, stream>>>(x, emb, wsf);
    fb_gather<<<(NN * 64) / 256, 256, 0, stream>>>(x, emb, wsf, out);
    fb_finalize<<<1, 1, 0, stream>>>(wsf, out);
  }
}

// Round 3
// 1711.881 us; speedup vs baseline: 1.4937x; 1.4937x over previous
//
#include <hip/hip_runtime.h>
#include <float.h>

typedef __attribute__((ext_vector_type(8))) short bf16x8;
typedef __attribute__((ext_vector_type(4))) float f32x4;
typedef unsigned long long u64;
typedef unsigned int u32;
typedef unsigned short u16;

#define NN 32768
#define KK 8192
#define DD 256
#define BM 128
#define BN 128
#define CSPLIT 4

// ---- ws byte offsets (fast path) ----
#define WB_ENORM   0
#define WB_XNORM   (WB_ENORM + KK*4)
#define WB_EH      (WB_XNORM + NN*4)
#define WB_EL      (WB_EH + KK*DD*2)
#define WB_LOSSP   (WB_EL + KK*DD*2)
#define WB_PARTIAL (WB_LOSSP + (NN/4)*4)
#define WS_NEED(LG2G) ((size_t)WB_PARTIAL + (size_t)NN * (KK >> (LG2G)) * 2)

// ---- fallback (round-1 validated) ws float offsets ----
#define FCSPLIT 4
#define WSF_ENORM 0
#define WSF_XNORM (KK)
#define WSF_CANDV (KK + NN)
#define WSF_CANDI (KK + NN + NN*FCSPLIT)
#define WSF_LOSS  (KK + NN + 2*NN*FCSPLIT)

__device__ inline void gload16(const void* g, void* l) {
  __builtin_amdgcn_global_load_lds(
      (const __attribute__((address_space(1))) u32*)g,
      (__attribute__((address_space(3))) u32*)l, 16, 0, 0);
}

__device__ inline u16 bf16_rtne(float f) {
  u32 u = __float_as_uint(f);
  return (u16)((u + 0x7FFFu + ((u >> 16) & 1u)) >> 16);
}

// d2 in [~160, ~380]; encode (d2-128)*256 with clamp (monotone; clamps are
// conservative-safe for the <=thr screening test)
__device__ inline u16 enc_d2(float d2) {
  int e = (int)((d2 - 128.f) * 256.f);
  e = e < 0 ? 0 : e;
  e = e > 65535 ? 65535 : e;
  return (u16)e;
}

// ---------------- prep: bf16 hi/lo planes + row norms (x and emb) ----------------
__global__ __launch_bounds__(256) void vq_prep(const float* __restrict__ x,
                                               const float* __restrict__ emb,
                                               u16* __restrict__ xh, u16* __restrict__ xl,
                                               u16* __restrict__ eh, u16* __restrict__ el,
                                               float* __restrict__ xnorm,
                                               float* __restrict__ enorm) {
  int gid = blockIdx.x * blockDim.x + threadIdx.x;
  int r = gid >> 6, lane = gid & 63;
  const float* src;
  u16 *ph, *pl;
  float* pn;
  if (r < NN) {
    src = x + (size_t)r * DD;
    ph = xh + (size_t)r * DD; pl = xl + (size_t)r * DD;
    pn = xnorm + r;
  } else {
    int rr = r - NN;
    if (rr >= KK) return;
    src = emb + (size_t)rr * DD;
    ph = eh + (size_t)rr * DD; pl = el + (size_t)rr * DD;
    pn = enorm + rr;
  }
  float4 v = ((const float4*)src)[lane];
  ushort4 h, l;
  h.x = bf16_rtne(v.x); l.x = bf16_rtne(v.x - __uint_as_float((u32)h.x << 16));
  h.y = bf16_rtne(v.y); l.y = bf16_rtne(v.y - __uint_as_float((u32)h.y << 16));
  h.z = bf16_rtne(v.z); l.z = bf16_rtne(v.z - __uint_as_float((u32)h.z << 16));
  h.w = bf16_rtne(v.w); l.w = bf16_rtne(v.w - __uint_as_float((u32)h.w << 16));
  ((ushort4*)ph)[lane] = h;
  ((ushort4*)pl)[lane] = l;
  float s = v.x * v.x + v.y * v.y + v.z * v.z + v.w * v.w;
#pragma unroll
  for (int off = 32; off > 0; off >>= 1) s += __shfl_down(s, off, 64);
  if (lane == 0) *pn = s;
}

// ---------------- main MFMA screening kernel (2-phase pipelined) ----------------
template <int LG2G>
__global__ __launch_bounds__(256) void vq_mfma(const u16* __restrict__ xh,
                                               const u16* __restrict__ xl,
                                               const u16* __restrict__ eh,
                                               const u16* __restrict__ el,
                                               const float* __restrict__ xnorm,
                                               const float* __restrict__ enorm,
                                               u16* __restrict__ partial) {
  __shared__ u16 lds[2][4][4][128][8];  // [buf][plane][kgrp][rowcol][8 bf16] = 64 KB
  const int tid = threadIdx.x;
  const int lane = tid & 63;
  const int wid = tid >> 6;
  const int wr = wid >> 1, wc = wid & 1;
  const int r0 = blockIdx.x * BM;
  const int cbase = blockIdx.y * (KK / CSPLIT);
  const int u_ = lane >> 4, t_ = lane & 15;
  const int NG = KK >> LG2G;

  const u16* plane_src = (wid == 0) ? xh : (wid == 1) ? xl : (wid == 2) ? eh : el;
  const size_t prow0 = (wid < 2) ? (size_t)r0 : (size_t)cbase;
  const bool is_e = (wid >= 2);

  // per-lane xnorm for the epilogue rows (loaded once)
  float xr[4][4];
#pragma unroll
  for (int mf = 0; mf < 4; ++mf)
#pragma unroll
    for (int q = 0; q < 4; ++q) xr[mf][q] = xnorm[r0 + wr * 64 + mf * 16 + u_ * 4 + q];

  f32x4 acc[4][4];
#pragma unroll
  for (int i = 0; i < 4; ++i)
#pragma unroll
    for (int j = 0; j < 4; ++j) acc[i][j] = (f32x4){0.f, 0.f, 0.f, 0.f};
  float en[4];

  const int NT = (KK / CSPLIT) / BN;  // 16 tiles
  const int STEPS = NT * 8;           // 128 steps

  auto STAGE = [&](int buf, int ct, int kc) {
    const u16* base = plane_src + (prow0 + (is_e ? (size_t)ct * BN : 0)) * DD + kc * 32;
#pragma unroll
    for (int i = 0; i < 8; ++i) {
      int li = i * 64 + lane;
      gload16(base + (size_t)(li & 127) * DD + (li >> 7) * 8,
              &lds[buf][wid][li >> 7][li & 127][0]);
    }
  };

  STAGE(0, 0, 0);
  __syncthreads();
  int cur = 0;

  for (int step = 0; step < STEPS; ++step) {
    const int ct = step >> 3, kc = step & 7;
    if (step + 1 < STEPS) STAGE(cur ^ 1, (step + 1) >> 3, (step + 1) & 7);
    if (kc == 0) {  // prefetch enorm for this tile's epilogue
      const int c0 = cbase + ct * BN;
#pragma unroll
      for (int nf = 0; nf < 4; ++nf) en[nf] = enorm[c0 + wc * 64 + nf * 16 + t_];
    }
    {  // compute current buffer: 16 ds_read_b128 + 48 MFMA
      bf16x8 bh[4], bl[4];
#pragma unroll
      for (int nf = 0; nf < 4; ++nf) {
        const int col = wc * 64 + nf * 16 + t_;
        bh[nf] = *(const bf16x8*)&lds[cur][2][u_][col][0];
        bl[nf] = *(const bf16x8*)&lds[cur][3][u_][col][0];
      }
#pragma unroll
      for (int mf = 0; mf < 4; ++mf) {
        const int rowl = wr * 64 + mf * 16 + t_;
        bf16x8 ah = *(const bf16x8*)&lds[cur][0][u_][rowl][0];
        bf16x8 al = *(const bf16x8*)&lds[cur][1][u_][rowl][0];
#pragma unroll
        for (int nf = 0; nf < 4; ++nf) {
          acc[mf][nf] = __builtin_amdgcn_mfma_f32_16x16x32_bf16(ah, bh[nf], acc[mf][nf], 0, 0, 0);
          acc[mf][nf] = __builtin_amdgcn_mfma_f32_16x16x32_bf16(ah, bl[nf], acc[mf][nf], 0, 0, 0);
          acc[mf][nf] = __builtin_amdgcn_mfma_f32_16x16x32_bf16(al, bh[nf], acc[mf][nf], 0, 0, 0);
        }
      }
    }
    if (kc == 7) {  // epilogue: group-min of approx d2, encode, plain store
      const int c0 = cbase + ct * BN;
#pragma unroll
      for (int mf = 0; mf < 4; ++mf) {
        float gm[4][4];
#pragma unroll
        for (int nf = 0; nf < 4; ++nf) {
#pragma unroll
          for (int q = 0; q < 4; ++q) {
            float d2 = fmaf(-2.f, acc[mf][nf][q], xr[mf][q]) + en[nf];
#pragma unroll
            for (int off = 1; off < 16; off <<= 1) d2 = fminf(d2, __shfl_xor(d2, off, 64));
            gm[nf][q] = d2;
          }
        }
        if (t_ == 0) {
          const int rowb = r0 + wr * 64 + mf * 16 + u_ * 4;
          if (LG2G == 4) {
#pragma unroll
            for (int nf = 0; nf < 4; ++nf) {
              const int g = (c0 + wc * 64 + nf * 16) >> 4;
#pragma unroll
              for (int q = 0; q < 4; ++q)
                partial[(size_t)(rowb + q) * NG + g] = enc_d2(gm[nf][q]);
            }
          } else {
#pragma unroll
            for (int nfp = 0; nfp < 4; nfp += 2) {
              const int g = (c0 + wc * 64 + nfp * 16) >> 5;
#pragma unroll
              for (int q = 0; q < 4; ++q)
                partial[(size_t)(rowb + q) * NG + g] = enc_d2(fminf(gm[nfp][q], gm[nfp + 1][q]));
            }
          }
        }
#pragma unroll
        for (int nf = 0; nf < 4; ++nf) acc[mf][nf] = (f32x4){0.f, 0.f, 0.f, 0.f};
      }
    }
    __syncthreads();
    cur ^= 1;
  }
}

// ---------------- fused post: select + exact rescore + gather + st + loss ----------------
template <int LG2G>
__global__ __launch_bounds__(256) void vq_post(const float* __restrict__ x,
                                               const float* __restrict__ emb,
                                               const float* __restrict__ xnorm,
                                               const float* __restrict__ enorm,
                                               const u16* __restrict__ partial,
                                               float* __restrict__ losspart,
                                               float* __restrict__ out) {
  __shared__ float lred[4];
  const int tid = threadIdx.x, lane = tid & 63, wid = tid >> 6;
  const int row = blockIdx.x * 4 + wid;
  constexpr int NG = KK >> LG2G;
  constexpr int NPER = NG >> 6;       // slots per lane: 8 or 4
  constexpr int GSZ = 1 << LG2G;

  // coalesced groupmin load
  u32 wbuf[NPER / 2];
  const u32* p32 = (const u32*)(partial + (size_t)row * NG) + lane * (NPER / 2);
#pragma unroll
  for (int i = 0; i < NPER / 2; ++i) wbuf[i] = p32[i];

  int mymin = 0xFFFF;
#pragma unroll
  for (int i = 0; i < NPER / 2; ++i) {
    mymin = min(mymin, (int)(wbuf[i] & 0xFFFFu));
    mymin = min(mymin, (int)(wbuf[i] >> 16));
  }
#pragma unroll
  for (int off = 1; off < 64; off <<= 1) mymin = min(mymin, __shfl_xor(mymin, off, 64));
  const int thr = mymin + 1;  // enc slack 1/256 = 3.9e-3 >> 2*eps bound

  u32 mask = 0;
#pragma unroll
  for (int i = 0; i < NPER / 2; ++i) {
    if ((int)(wbuf[i] & 0xFFFFu) <= thr) mask |= 1u << (2 * i);
    if ((int)(wbuf[i] >> 16) <= thr) mask |= 1u << (2 * i + 1);
  }

  const float xx = xnorm[row];
  const float* xrow = x + (size_t)row * DD;
  u64 best = ~0ull;
  u64 lanesw = __ballot(mask != 0);
  while (lanesw) {
    int src = __ffsll((unsigned long long)lanesw) - 1;
    lanesw &= lanesw - 1;
    u32 lm = __shfl(mask, src, 64);
    while (lm) {
      int s = __ffs(lm) - 1;
      lm &= lm - 1;
      const int g = src * NPER + s;
      const int code = (g << LG2G) + (lane & (GSZ - 1));
      const float* erow = emb + (size_t)code * DD;
      float a = 0.f;
      // bit-exact sequential chain (ascending d) — matches validated reference path
#pragma unroll 4
      for (int d = 0; d < DD; d += 4) {
        float4 xv = *(const float4*)(xrow + d);
        float4 ev = *(const float4*)(erow + d);
        a = fmaf(xv.x, ev.x, a);
        a = fmaf(xv.y, ev.y, a);
        a = fmaf(xv.z, ev.z, a);
        a = fmaf(xv.w, ev.w, a);
      }
      float d2 = fmaf(-2.f, a, xx) + enorm[code];
      u64 pk = ((u64)__float_as_uint(d2) << 32) | (u32)code;
      if (lane >= GSZ) pk = ~0ull;
      if (pk < best) best = pk;
    }
  }
#pragma unroll
  for (int off = 1; off < 64; off <<= 1) {
    u64 o = __shfl_xor(best, off, 64);
    if (o < best) best = o;
  }
  const int bi = (int)(u32)(best & 0xFFFFFFFFull);

  if (lane == 0) out[(size_t)NN * DD + 2 + row] = (float)bi;
  float4 qv = ((const float4*)(emb + (size_t)bi * DD))[lane];
  float4 xv = ((const float4*)xrow)[lane];
  float4 st;
  st.x = xv.x + (qv.x - xv.x);
  st.y = xv.y + (qv.y - xv.y);
  st.z = xv.z + (qv.z - xv.z);
  st.w = xv.w + (qv.w - xv.w);
  ((float4*)(out + (size_t)row * DD))[lane] = st;

  float dx = xv.x - qv.x, dy = xv.y - qv.y, dz = xv.z - qv.z, dw = xv.w - qv.w;
  float s2 = dx * dx + dy * dy + dz * dz + dw * dw;
#pragma unroll
  for (int off = 32; off > 0; off >>= 1) s2 += __shfl_down(s2, off, 64);
  if (lane == 0) lred[wid] = s2;
  __syncthreads();
  if (tid == 0) losspart[blockIdx.x] = lred[0] + lred[1] + lred[2] + lred[3];
}

__global__ __launch_bounds__(256) void vq_finalize(const float* __restrict__ losspart,
                                                   float* __restrict__ out) {
  __shared__ float l[256];
  float s = 0.f;
  for (int i = threadIdx.x; i < NN / 4; i += 256) s += losspart[i];
  l[threadIdx.x] = s;
  __syncthreads();
  for (int o = 128; o > 0; o >>= 1) {
    if (threadIdx.x < o) l[threadIdx.x] += l[threadIdx.x + o];
    __syncthreads();
  }
  if (threadIdx.x == 0) {
    float loss = l[0] / (float)((size_t)NN * DD);
    out[(size_t)NN * DD] = loss;
    out[(size_t)NN * DD + 1] = loss;
  }
}

// ---------------- fallback path (round-1 validated, f32 VALU) ----------------
__global__ __launch_bounds__(256) void fb_norms(const float* __restrict__ x,
                                                const float* __restrict__ emb,
                                                float* __restrict__ ws) {
  int gid = blockIdx.x * blockDim.x + threadIdx.x;
  int wave = gid >> 6, lane = gid & 63;
  const float* src;
  float* dst;
  if (wave < KK) { src = emb + (size_t)wave * DD; dst = ws + WSF_ENORM + wave; }
  else {
    int r = wave - KK;
    if (r >= NN) return;
    src = x + (size_t)r * DD; dst = ws + WSF_XNORM + r;
  }
  float4 v = ((const float4*)src)[lane];
  float s = v.x * v.x + v.y * v.y + v.z * v.z + v.w * v.w;
#pragma unroll
  for (int off = 32; off > 0; off >>= 1) s += __shfl_down(s, off, 64);
  if (lane == 0) *dst = s;
}

__global__ __launch_bounds__(256) void fb_argmin(const float* __restrict__ x,
                                                 const float* __restrict__ emb,
                                                 float* __restrict__ ws) {
  const float* enorm = ws + WSF_ENORM;
  const float* xnorm = ws + WSF_XNORM;
  float* candv = ws + WSF_CANDV;
  int* candi = (int*)(ws + WSF_CANDI);
  __shared__ float As[32][BM + 4];
  __shared__ float Bs[32][BN + 4];
  const int tid = threadIdx.x;
  const int tr = tid >> 4, tc = tid & 15;
  const int r0 = blockIdx.x * BM;
  const int split = blockIdx.y;
  const int cb = split * (KK / FCSPLIT);
  float xr[8];
  {
    const float4* p = (const float4*)(xnorm + r0 + tr * 8);
    float4 a = p[0], b = p[1];
    xr[0] = a.x; xr[1] = a.y; xr[2] = a.z; xr[3] = a.w;
    xr[4] = b.x; xr[5] = b.y; xr[6] = b.z; xr[7] = b.w;
  }
  float bestv[8];
  int besti[8];
#pragma unroll
  for (int i = 0; i < 8; i++) { bestv[i] = FLT_MAX; besti[i] = 0; }
  for (int ct = 0; ct < (KK / FCSPLIT) / BN; ++ct) {
    const int c0 = cb + ct * BN;
    float acc[8][8];
#pragma unroll
    for (int i = 0; i < 8; i++)
#pragma unroll
      for (int j = 0; j < 8; j++) acc[i][j] = 0.f;
    for (int kc = 0; kc < DD; kc += 32) {
      __syncthreads();
      const int rrow = tid >> 3, dg = tid & 7;
#pragma unroll
      for (int p = 0; p < 4; ++p) {
        int rw = p * 32 + rrow;
        float4 av = ((const float4*)(x + (size_t)(r0 + rw) * DD + kc))[dg];
        float4 bv = ((const float4*)(emb + (size_t)(c0 + rw) * DD + kc))[dg];
        As[dg * 4 + 0][rw] = av.x; As[dg * 4 + 1][rw] = av.y;
        As[dg * 4 + 2][rw] = av.z; As[dg * 4 + 3][rw] = av.w;
        Bs[dg * 4 + 0][rw] = bv.x; Bs[dg * 4 + 1][rw] = bv.y;
        Bs[dg * 4 + 2][rw] = bv.z; Bs[dg * 4 + 3][rw] = bv.w;
      }
      __syncthreads();
#pragma unroll 4
      for (int kk = 0; kk < 32; ++kk) {
        float4 a0 = *(const float4*)&As[kk][tr * 8];
        float4 a1 = *(const float4*)&As[kk][tr * 8 + 4];
        float4 b0 = *(const float4*)&Bs[kk][tc * 8];
        float4 b1 = *(const float4*)&Bs[kk][tc * 8 + 4];
        float a[8] = {a0.x, a0.y, a0.z, a0.w, a1.x, a1.y, a1.z, a1.w};
        float b[8] = {b0.x, b0.y, b0.z, b0.w, b1.x, b1.y, b1.z, b1.w};
#pragma unroll
        for (int i = 0; i < 8; i++)
#pragma unroll
          for (int j = 0; j < 8; j++) acc[i][j] = fmaf(a[i], b[j], acc[i][j]);
      }
    }
    float en[8];
    {
      const float4* p = (const float4*)(enorm + c0 + tc * 8);
      float4 a = p[0], b = p[1];
      en[0] = a.x; en[1] = a.y; en[2] = a.z; en[3] = a.w;
      en[4] = b.x; en[5] = b.y; en[6] = b.z; en[7] = b.w;
    }
#pragma unroll
    for (int i = 0; i < 8; i++)
#pragma unroll
      for (int j = 0; j < 8; j++) {
        float t = fmaf(-2.f, acc[i][j], xr[i]);
        float d2 = t + en[j];
        int code = c0 + tc * 8 + j;
        if (d2 < bestv[i]) { bestv[i] = d2; besti[i] = code; }
      }
  }
#pragma unroll
  for (int i = 0; i < 8; i++) {
    float v = bestv[i];
    int bi = besti[i];
#pragma unroll
    for (int off = 1; off < 16; off <<= 1) {
      float v2 = __shfl_xor(v, off, 64);
      int i2 = __shfl_xor(bi, off, 64);
      if (v2 < v || (v2 == v && i2 < bi)) { v = v2; bi = i2; }
    }
    if (tc == 0) {
      int row = r0 + tr * 8 + i;
      candv[row * FCSPLIT + split] = v;
      candi[row * FCSPLIT + split] = bi;
    }
  }
}

__global__ __launch_bounds__(256) void fb_gather(const float* __restrict__ x,
                                                 const float* __restrict__ emb,
                                                 float* __restrict__ ws,
                                                 float* __restrict__ out) {
  const float* candv = ws + WSF_CANDV;
  const int* candi = (const int*)(ws + WSF_CANDI);
  float* loss_acc = ws + WSF_LOSS;
  int gid = blockIdx.x * blockDim.x + threadIdx.x;
  int row = gid >> 6, lane = gid & 63;
  if (row >= NN) return;
  float bv = candv[row * FCSPLIT];
  int bi = candi[row * FCSPLIT];
#pragma unroll
  for (int s = 1; s < FCSPLIT; s++) {
    float v = candv[row * FCSPLIT + s];
    int ii = candi[row * FCSPLIT + s];
    if (v < bv || (v == bv && ii < bi)) { bv = v; bi = ii; }
  }
  if (lane == 0) out[(size_t)NN * DD + 2 + row] = (float)bi;
  float4 qv = ((const float4*)(emb + (size_t)bi * DD))[lane];
  float4 xv = ((const float4*)(x + (size_t)row * DD))[lane];
  float4 st;
  st.x = xv.x + (qv.x - xv.x);
  st.y = xv.y + (qv.y - xv.y);
  st.z = xv.z + (qv.z - xv.z);
  st.w = xv.w + (qv.w - xv.w);
  ((float4*)(out + (size_t)row * DD))[lane] = st;
  float dx = xv.x - qv.x, dy = xv.y - qv.y, dz = xv.z - qv.z, dw = xv.w - qv.w;
  float s2 = dx * dx + dy * dy + dz * dz + dw * dw;
#pragma unroll
  for (int off = 32; off > 0; off >>= 1) s2 += __shfl_down(s2, off, 64);
  if (lane == 0) atomicAdd(loss_acc, s2);
}

__global__ void fb_finalize(const float* __restrict__ ws, float* __restrict__ out) {
  float loss = ws[WSF_LOSS] / (float)((size_t)NN * DD);
  out[(size_t)NN * DD] = loss;
  out[(size_t)NN * DD + 1] = loss;
}

// ---------------- launch ----------------
template <int LG2G>
static void launch_fast(const float* x, const float* emb, float* out, char* ws,
                        hipStream_t stream) {
  float* enorm = (float*)(ws + WB_ENORM);
  float* xnorm = (float*)(ws + WB_XNORM);
  u16* eh = (u16*)(ws + WB_EH);
  u16* el = (u16*)(ws + WB_EL);
  float* losspart = (float*)(ws + WB_LOSSP);
  u16* partial = (u16*)(ws + WB_PARTIAL);
  u16* xh = (u16*)out;                       // x planes live in out's quantized region
  u16* xl = xh + (size_t)NN * DD;            // overwritten by vq_post afterwards

  vq_prep<<<(NN + KK) / 4, 256, 0, stream>>>(x, emb, xh, xl, eh, el, xnorm, enorm);
  vq_mfma<LG2G><<<dim3(NN / BM, CSPLIT), 256, 0, stream>>>(xh, xl, eh, el, xnorm, enorm, partial);
  vq_post<LG2G><<<NN / 4, 256, 0, stream>>>(x, emb, xnorm, enorm, partial, losspart, out);
  vq_finalize<<<1, 256, 0, stream>>>(losspart, out);
}

extern "C" void kernel_launch(void* const* d_in, const int* in_sizes, int n_in,
                              void* d_out, int out_size, void* d_ws, size_t ws_size,
                              hipStream_t stream) {
  const float* x = (const float*)d_in[0];
  const float* emb = (const float*)d_in[1];
  float* out = (float*)d_out;
  char* ws = (char*)d_ws;

  if (ws_size >= WS_NEED(4)) {
    launch_fast<4>(x, emb, out, ws, stream);          // 16-code groups, 42.1 MB ws
  } else if (ws_size >= WS_NEED(5)) {
    launch_fast<5>(x, emb, out, ws, stream);          // 32-code groups, 25.4 MB ws
  } else {
    float* wsf = (float*)d_ws;
    hipMemsetAsync(ws + (size_t)WSF_LOSS * 4, 0, 4, stream);
    fb_norms<<<((KK + NN) * 64) / 256, 256, 0, stream>>>(x, emb, wsf);
    fb_argmin<<<dim3(NN / BM, FCSPLIT), 256, 0, stream>>>(x, emb, wsf);
    fb_gather<<<(NN * 64) / 256, 256, 0, stream>>>(x, emb, wsf, out);
    fb_finalize<<<1, 1, 0, stream>>>(wsf, out);
  }
}

// Round 4
// 1070.223 us; speedup vs baseline: 2.3893x; 1.5996x over previous
//
#include <hip/hip_runtime.h>
#include <float.h>

typedef __attribute__((ext_vector_type(8))) _Float16 f16x8;
typedef __attribute__((ext_vector_type(4))) float f32x4;
typedef unsigned long long u64;
typedef unsigned int u32;
typedef unsigned short u16;

#define NN 32768
#define KK 8192
#define DD 256
#define BM 128
#define BN 128
#define CSPLIT 4
#define NG 128          // 64-code groups
#define GSZ 64

// ---- ws byte offsets (fast path) ----
#define WB_ENORM   0
#define WB_XNORM   (WB_ENORM + KK*4)
#define WB_EF      (WB_XNORM + NN*4)
#define WB_XF      (WB_EF + KK*DD*2)
#define WB_LOSSP   (WB_XF + (size_t)NN*DD*2)
#define WB_PARTIAL (WB_LOSSP + (NN/4)*4)
#define WB_NEED    ((size_t)WB_PARTIAL + (size_t)NN*NG*2)

// ---- fallback (round-1 validated) ws float offsets ----
#define FCSPLIT 4
#define WSF_ENORM 0
#define WSF_XNORM (KK)
#define WSF_CANDV (KK + NN)
#define WSF_CANDI (KK + NN + NN*FCSPLIT)
#define WSF_LOSS  (KK + NN + 2*NN*FCSPLIT)

__device__ inline void gload16(const void* g, void* l) {
  __builtin_amdgcn_global_load_lds(
      (const __attribute__((address_space(1))) u32*)g,
      (__attribute__((address_space(3))) u32*)l, 16, 0, 0);
}

// d2 in [~140, ~380]; monotone clamped encode; clamps are correctness-safe
// (clamped-low groups all pass screening and get exact-rescored).
__device__ inline u16 enc_d2(float d2) {
  int e = (int)((d2 - 128.f) * 256.f);
  e = e < 0 ? 0 : e;
  e = e > 65535 ? 65535 : e;
  return (u16)e;
}

// ---------------- prep: f16 planes + row norms (x and emb) ----------------
__global__ __launch_bounds__(256) void vq_prep(const float* __restrict__ x,
                                               const float* __restrict__ emb,
                                               u16* __restrict__ xf, u16* __restrict__ ef,
                                               float* __restrict__ xnorm,
                                               float* __restrict__ enorm) {
  int gid = blockIdx.x * blockDim.x + threadIdx.x;
  int r = gid >> 6, lane = gid & 63;
  const float* src;
  u16* pf;
  float* pn;
  if (r < NN) {
    src = x + (size_t)r * DD;
    pf = xf + (size_t)r * DD;
    pn = xnorm + r;
  } else {
    int rr = r - NN;
    if (rr >= KK) return;
    src = emb + (size_t)rr * DD;
    pf = ef + (size_t)rr * DD;
    pn = enorm + rr;
  }
  float4 v = ((const float4*)src)[lane];
  ushort4 h;
  _Float16 t0 = (_Float16)v.x; h.x = *(const u16*)&t0;
  _Float16 t1 = (_Float16)v.y; h.y = *(const u16*)&t1;
  _Float16 t2 = (_Float16)v.z; h.z = *(const u16*)&t2;
  _Float16 t3 = (_Float16)v.w; h.w = *(const u16*)&t3;
  ((ushort4*)pf)[lane] = h;
  float s = v.x * v.x + v.y * v.y + v.z * v.z + v.w * v.w;
#pragma unroll
  for (int off = 32; off > 0; off >>= 1) s += __shfl_down(s, off, 64);
  if (lane == 0) *pn = s;
}

// ---------------- main MFMA screening kernel (f16 single-product) ----------------
__global__ __launch_bounds__(256, 4) void vq_mfma(const u16* __restrict__ xf,
                                                  const u16* __restrict__ ef,
                                                  const float* __restrict__ xnorm,
                                                  const float* __restrict__ enorm,
                                                  u16* __restrict__ partial) {
  // flat f = plane*512 + kgrp*128 + row ; 16B per f ; 16 KB/buffer
  __shared__ u16 lds[2][1024][8];
  const int tid = threadIdx.x;
  const int lane = tid & 63;
  const int wid = tid >> 6;
  const int wr = wid >> 1, wc = wid & 1;
  const int r0 = blockIdx.x * BM;
  const int cbase = blockIdx.y * (KK / CSPLIT);
  const int u_ = lane >> 4, t_ = lane & 15;

  f32x4 acc[4][4];
#pragma unroll
  for (int i = 0; i < 4; ++i)
#pragma unroll
    for (int j = 0; j < 4; ++j) acc[i][j] = (f32x4){0.f, 0.f, 0.f, 0.f};

  auto STAGE = [&](int buf, int ct, int kc) {
    const int c0 = cbase + ct * BN;
#pragma unroll
    for (int i = 0; i < 4; ++i) {
      const int f = wid * 256 + i * 64 + lane;
      const int plane = f >> 9, kgrp = (f >> 7) & 3, row = f & 127;
      const u16* src = plane ? (ef + (size_t)(c0 + row) * DD)
                             : (xf + (size_t)(r0 + row) * DD);
      gload16(src + kc * 32 + kgrp * 8, &lds[buf][f][0]);
    }
  };

  STAGE(0, 0, 0);
  __syncthreads();
  int cur = 0;

  for (int step = 0; step < 128; ++step) {
    const int ct = step >> 3, kc = step & 7;
    if (step + 1 < 128) STAGE(cur ^ 1, (step + 1) >> 3, (step + 1) & 7);

    // compute current buffer: 8 ds_read_b128 + 16 MFMA
    f16x8 bh[4];
#pragma unroll
    for (int nf = 0; nf < 4; ++nf)
      bh[nf] = *(const f16x8*)&lds[cur][512 + u_ * 128 + wc * 64 + nf * 16 + t_][0];
#pragma unroll
    for (int mf = 0; mf < 4; ++mf) {
      f16x8 ah = *(const f16x8*)&lds[cur][u_ * 128 + wr * 64 + mf * 16 + t_][0];
#pragma unroll
      for (int nf = 0; nf < 4; ++nf)
        acc[mf][nf] = __builtin_amdgcn_mfma_f32_16x16x32_f16(ah, bh[nf], acc[mf][nf], 0, 0, 0);
    }

    if (kc == 7) {  // tile epilogue: 64-code group min -> encoded partial
      const int c0 = cbase + ct * BN;
      const int g = (c0 + wc * 64) >> 6;
      float en[4];
#pragma unroll
      for (int nf = 0; nf < 4; ++nf) en[nf] = enorm[c0 + wc * 64 + nf * 16 + t_];
#pragma unroll
      for (int mf = 0; mf < 4; ++mf) {
        const int rowb = r0 + wr * 64 + mf * 16 + u_ * 4;
#pragma unroll
        for (int q = 0; q < 4; ++q) {
          const float xx = xnorm[rowb + q];
          float d0 = fmaf(-2.f, acc[mf][0][q], xx) + en[0];
          float d1 = fmaf(-2.f, acc[mf][1][q], xx) + en[1];
          float d2 = fmaf(-2.f, acc[mf][2][q], xx) + en[2];
          float d3 = fmaf(-2.f, acc[mf][3][q], xx) + en[3];
          float gm = fminf(fminf(d0, d1), fminf(d2, d3));
#pragma unroll
          for (int off = 1; off < 16; off <<= 1) gm = fminf(gm, __shfl_xor(gm, off, 64));
          if (t_ == 0) partial[(size_t)(rowb + q) * NG + g] = enc_d2(gm);
        }
#pragma unroll
        for (int nf = 0; nf < 4; ++nf) acc[mf][nf] = (f32x4){0.f, 0.f, 0.f, 0.f};
      }
    }
    __syncthreads();
    cur ^= 1;
  }
}

// ---------------- fused post: select + exact rescore + gather + st + loss ----------------
__global__ __launch_bounds__(256) void vq_post(const float* __restrict__ x,
                                               const float* __restrict__ emb,
                                               const float* __restrict__ xnorm,
                                               const float* __restrict__ enorm,
                                               const u16* __restrict__ partial,
                                               float* __restrict__ losspart,
                                               float* __restrict__ out) {
  __shared__ float lred[4];
  const int tid = threadIdx.x, lane = tid & 63, wid = tid >> 6;
  const int row = blockIdx.x * 4 + wid;

  // coalesced groupmin load: 128 u16 per row = 1 u32 per lane
  const u32 wbuf = ((const u32*)(partial + (size_t)row * NG))[lane];
  int mymin = min((int)(wbuf & 0xFFFFu), (int)(wbuf >> 16));
#pragma unroll
  for (int off = 1; off < 64; off <<= 1) mymin = min(mymin, __shfl_xor(mymin, off, 64));
  const int thr = mymin + 1;  // provably-safe slack: f16 worst-case err < 1 enc unit

  u32 mask = 0;
  if ((int)(wbuf & 0xFFFFu) <= thr) mask |= 1u;
  if ((int)(wbuf >> 16) <= thr) mask |= 2u;

  const float xx = xnorm[row];
  const float* xrow = x + (size_t)row * DD;
  u64 best = ~0ull;
  u64 lanesw = __ballot(mask != 0);
  while (lanesw) {
    int src = __ffsll((unsigned long long)lanesw) - 1;
    lanesw &= lanesw - 1;
    u32 lm = __shfl(mask, src, 64);
    while (lm) {
      int s = __ffs(lm) - 1;
      lm &= lm - 1;
      const int code = ((src * 2 + s) << 6) + lane;  // 64 codes, one per lane
      const float* erow = emb + (size_t)code * DD;
      float a = 0.f;
      // bit-exact sequential chain (ascending d) — matches validated reference path
#pragma unroll 4
      for (int d = 0; d < DD; d += 4) {
        float4 xv = *(const float4*)(xrow + d);
        float4 ev = *(const float4*)(erow + d);
        a = fmaf(xv.x, ev.x, a);
        a = fmaf(xv.y, ev.y, a);
        a = fmaf(xv.z, ev.z, a);
        a = fmaf(xv.w, ev.w, a);
      }
      float d2 = fmaf(-2.f, a, xx) + enorm[code];
      u64 pk = ((u64)__float_as_uint(d2) << 32) | (u32)code;
      if (pk < best) best = pk;
    }
  }
#pragma unroll
  for (int off = 1; off < 64; off <<= 1) {
    u64 o = __shfl_xor(best, off, 64);
    if (o < best) best = o;
  }
  const int bi = (int)(u32)(best & 0xFFFFFFFFull);

  if (lane == 0) out[(size_t)NN * DD + 2 + row] = (float)bi;
  float4 qv = ((const float4*)(emb + (size_t)bi * DD))[lane];
  float4 xv = ((const float4*)xrow)[lane];
  float4 st;
  st.x = xv.x + (qv.x - xv.x);
  st.y = xv.y + (qv.y - xv.y);
  st.z = xv.z + (qv.z - xv.z);
  st.w = xv.w + (qv.w - xv.w);
  ((float4*)(out + (size_t)row * DD))[lane] = st;

  float dx = xv.x - qv.x, dy = xv.y - qv.y, dz = xv.z - qv.z, dw = xv.w - qv.w;
  float s2 = dx * dx + dy * dy + dz * dz + dw * dw;
#pragma unroll
  for (int off = 32; off > 0; off >>= 1) s2 += __shfl_down(s2, off, 64);
  if (lane == 0) lred[wid] = s2;
  __syncthreads();
  if (tid == 0) losspart[blockIdx.x] = lred[0] + lred[1] + lred[2] + lred[3];
}

__global__ __launch_bounds__(256) void vq_finalize(const float* __restrict__ losspart,
                                                   float* __restrict__ out) {
  __shared__ float l[256];
  float s = 0.f;
  for (int i = threadIdx.x; i < NN / 4; i += 256) s += losspart[i];
  l[threadIdx.x] = s;
  __syncthreads();
  for (int o = 128; o > 0; o >>= 1) {
    if (threadIdx.x < o) l[threadIdx.x] += l[threadIdx.x + o];
    __syncthreads();
  }
  if (threadIdx.x == 0) {
    float loss = l[0] / (float)((size_t)NN * DD);
    out[(size_t)NN * DD] = loss;
    out[(size_t)NN * DD + 1] = loss;
  }
}

// ---------------- fallback path (round-1 validated, f32 VALU) ----------------
__global__ __launch_bounds__(256) void fb_norms(const float* __restrict__ x,
                                                const float* __restrict__ emb,
                                                float* __restrict__ ws) {
  int gid = blockIdx.x * blockDim.x + threadIdx.x;
  int wave = gid >> 6, lane = gid & 63;
  const float* src;
  float* dst;
  if (wave < KK) { src = emb + (size_t)wave * DD; dst = ws + WSF_ENORM + wave; }
  else {
    int r = wave - KK;
    if (r >= NN) return;
    src = x + (size_t)r * DD; dst = ws + WSF_XNORM + r;
  }
  float4 v = ((const float4*)src)[lane];
  float s = v.x * v.x + v.y * v.y + v.z * v.z + v.w * v.w;
#pragma unroll
  for (int off = 32; off > 0; off >>= 1) s += __shfl_down(s, off, 64);
  if (lane == 0) *dst = s;
}

__global__ __launch_bounds__(256) void fb_argmin(const float* __restrict__ x,
                                                 const float* __restrict__ emb,
                                                 float* __restrict__ ws) {
  const float* enorm = ws + WSF_ENORM;
  const float* xnorm = ws + WSF_XNORM;
  float* candv = ws + WSF_CANDV;
  int* candi = (int*)(ws + WSF_CANDI);
  __shared__ float As[32][BM + 4];
  __shared__ float Bs[32][BN + 4];
  const int tid = threadIdx.x;
  const int tr = tid >> 4, tc = tid & 15;
  const int r0 = blockIdx.x * BM;
  const int split = blockIdx.y;
  const int cb = split * (KK / FCSPLIT);
  float xr[8];
  {
    const float4* p = (const float4*)(xnorm + r0 + tr * 8);
    float4 a = p[0], b = p[1];
    xr[0] = a.x; xr[1] = a.y; xr[2] = a.z; xr[3] = a.w;
    xr[4] = b.x; xr[5] = b.y; xr[6] = b.z; xr[7] = b.w;
  }
  float bestv[8];
  int besti[8];
#pragma unroll
  for (int i = 0; i < 8; i++) { bestv[i] = FLT_MAX; besti[i] = 0; }
  for (int ct = 0; ct < (KK / FCSPLIT) / BN; ++ct) {
    const int c0 = cb + ct * BN;
    float acc[8][8];
#pragma unroll
    for (int i = 0; i < 8; i++)
#pragma unroll
      for (int j = 0; j < 8; j++) acc[i][j] = 0.f;
    for (int kc = 0; kc < DD; kc += 32) {
      __syncthreads();
      const int rrow = tid >> 3, dg = tid & 7;
#pragma unroll
      for (int p = 0; p < 4; ++p) {
        int rw = p * 32 + rrow;
        float4 av = ((const float4*)(x + (size_t)(r0 + rw) * DD + kc))[dg];
        float4 bv = ((const float4*)(emb + (size_t)(c0 + rw) * DD + kc))[dg];
        As[dg * 4 + 0][rw] = av.x; As[dg * 4 + 1][rw] = av.y;
        As[dg * 4 + 2][rw] = av.z; As[dg * 4 + 3][rw] = av.w;
        Bs[dg * 4 + 0][rw] = bv.x; Bs[dg * 4 + 1][rw] = bv.y;
        Bs[dg * 4 + 2][rw] = bv.z; Bs[dg * 4 + 3][rw] = bv.w;
      }
      __syncthreads();
#pragma unroll 4
      for (int kk = 0; kk < 32; ++kk) {
        float4 a0 = *(const float4*)&As[kk][tr * 8];
        float4 a1 = *(const float4*)&As[kk][tr * 8 + 4];
        float4 b0 = *(const float4*)&Bs[kk][tc * 8];
        float4 b1 = *(const float4*)&Bs[kk][tc * 8 + 4];
        float a[8] = {a0.x, a0.y, a0.z, a0.w, a1.x, a1.y, a1.z, a1.w};
        float b[8] = {b0.x, b0.y, b0.z, b0.w, b1.x, b1.y, b1.z, b1.w};
#pragma unroll
        for (int i = 0; i < 8; i++)
#pragma unroll
          for (int j = 0; j < 8; j++) acc[i][j] = fmaf(a[i], b[j], acc[i][j]);
      }
    }
    float en[8];
    {
      const float4* p = (const float4*)(enorm + c0 + tc * 8);
      float4 a = p[0], b = p[1];
      en[0] = a.x; en[1] = a.y; en[2] = a.z; en[3] = a.w;
      en[4] = b.x; en[5] = b.y; en[6] = b.z; en[7] = b.w;
    }
#pragma unroll
    for (int i = 0; i < 8; i++)
#pragma unroll
      for (int j = 0; j < 8; j++) {
        float t = fmaf(-2.f, acc[i][j], xr[i]);
        float d2 = t + en[j];
        int code = c0 + tc * 8 + j;
        if (d2 < bestv[i]) { bestv[i] = d2; besti[i] = code; }
      }
  }
#pragma unroll
  for (int i = 0; i < 8; i++) {
    float v = bestv[i];
    int bi = besti[i];
#pragma unroll
    for (int off = 1; off < 16; off <<= 1) {
      float v2 = __shfl_xor(v, off, 64);
      int i2 = __shfl_xor(bi, off, 64);
      if (v2 < v || (v2 == v && i2 < bi)) { v = v2; bi = i2; }
    }
    if (tc == 0) {
      int row = r0 + tr * 8 + i;
      candv[row * FCSPLIT + split] = v;
      candi[row * FCSPLIT + split] = bi;
    }
  }
}

__global__ __launch_bounds__(256) void fb_gather(const float* __restrict__ x,
                                                 const float* __restrict__ emb,
                                                 float* __restrict__ ws,
                                                 float* __restrict__ out) {
  const float* candv = ws + WSF_CANDV;
  const int* candi = (const int*)(ws + WSF_CANDI);
  float* loss_acc = ws + WSF_LOSS;
  int gid = blockIdx.x * blockDim.x + threadIdx.x;
  int row = gid >> 6, lane = gid & 63;
  if (row >= NN) return;
  float bv = candv[row * FCSPLIT];
  int bi = candi[row * FCSPLIT];
#pragma unroll
  for (int s = 1; s < FCSPLIT; s++) {
    float v = candv[row * FCSPLIT + s];
    int ii = candi[row * FCSPLIT + s];
    if (v < bv || (v == bv && ii < bi)) { bv = v; bi = ii; }
  }
  if (lane == 0) out[(size_t)NN * DD + 2 + row] = (float)bi;
  float4 qv = ((const float4*)(emb + (size_t)bi * DD))[lane];
  float4 xv = ((const float4*)(x + (size_t)row * DD))[lane];
  float4 st;
  st.x = xv.x + (qv.x - xv.x);
  st.y = xv.y + (qv.y - xv.y);
  st.z = xv.z + (qv.z - xv.z);
  st.w = xv.w + (qv.w - xv.w);
  ((float4*)(out + (size_t)row * DD))[lane] = st;
  float dx = xv.x - qv.x, dy = xv.y - qv.y, dz = xv.z - qv.z, dw = xv.w - qv.w;
  float s2 = dx * dx + dy * dy + dz * dz + dw * dw;
#pragma unroll
  for (int off = 32; off > 0; off >>= 1) s2 += __shfl_down(s2, off, 64);
  if (lane == 0) atomicAdd(loss_acc, s2);
}

__global__ void fb_finalize(const float* __restrict__ ws, float* __restrict__ out) {
  float loss = ws[WSF_LOSS] / (float)((size_t)NN * DD);
  out[(size_t)NN * DD] = loss;
  out[(size_t)NN * DD + 1] = loss;
}

// ---------------- launch ----------------
extern "C" void kernel_launch(void* const* d_in, const int* in_sizes, int n_in,
                              void* d_out, int out_size, void* d_ws, size_t ws_size,
                              hipStream_t stream) {
  const float* x = (const float*)d_in[0];
  const float* emb = (const float*)d_in[1];
  float* out = (float*)d_out;
  char* ws = (char*)d_ws;

  if (ws_size >= WB_NEED) {
    float* enorm = (float*)(ws + WB_ENORM);
    float* xnorm = (float*)(ws + WB_XNORM);
    u16* ef = (u16*)(ws + WB_EF);
    u16* xf = (u16*)(ws + WB_XF);
    float* losspart = (float*)(ws + WB_LOSSP);
    u16* partial = (u16*)(ws + WB_PARTIAL);

    vq_prep<<<(NN + KK) / 4, 256, 0, stream>>>(x, emb, xf, ef, xnorm, enorm);
    vq_mfma<<<dim3(NN / BM, CSPLIT), 256, 0, stream>>>(xf, ef, xnorm, enorm, partial);
    vq_post<<<NN / 4, 256, 0, stream>>>(x, emb, xnorm, enorm, partial, losspart, out);
    vq_finalize<<<1, 256, 0, stream>>>(losspart, out);
  } else {
    float* wsf = (float*)d_ws;
    hipMemsetAsync(ws + (size_t)WSF_LOSS * 4, 0, 4, stream);
    fb_norms<<<((KK + NN) * 64) / 256, 256, 0, stream>>>(x, emb, wsf);
    fb_argmin<<<dim3(NN / BM, FCSPLIT), 256, 0, stream>>>(x, emb, wsf);
    fb_gather<<<(NN * 64) / 256, 256, 0, stream>>>(x, emb, wsf, out);
    fb_finalize<<<1, 1, 0, stream>>>(wsf, out);
  }
}

// Round 5
// 764.289 us; speedup vs baseline: 3.3457x; 1.4003x over previous
//
#include <hip/hip_runtime.h>
#include <float.h>

typedef __attribute__((ext_vector_type(8))) _Float16 f16x8;
typedef __attribute__((ext_vector_type(4))) float f32x4;
typedef unsigned long long u64;
typedef unsigned int u32;
typedef unsigned short u16;

#define NN 32768
#define KK 8192
#define DD 256
#define BM 128
#define BN 128
#define CSPLIT 4
#define NG 128          // 64-code groups

// ---- ws byte offsets (fast path) ~20.4 MB ----
#define WB_ENORM   0
#define WB_XNORM   (WB_ENORM + KK*4)
#define WB_EF      (WB_XNORM + NN*4)
#define WB_ET      (WB_EF + KK*DD*2)
#define WB_LOSSP   (WB_ET + (size_t)KK*DD*4)
#define WB_PARTIAL (WB_LOSSP + (NN/4)*4)
#define WB_NEED    ((size_t)WB_PARTIAL + (size_t)NN*NG*2)

// ---- fallback (round-1 validated) ws float offsets ----
#define FCSPLIT 4
#define WSF_ENORM 0
#define WSF_XNORM (KK)
#define WSF_CANDV (KK + NN)
#define WSF_CANDI (KK + NN + NN*FCSPLIT)
#define WSF_LOSS  (KK + NN + 2*NN*FCSPLIT)

__device__ inline void gload16(const void* g, void* l) {
  __builtin_amdgcn_global_load_lds(
      (const __attribute__((address_space(1))) u32*)g,
      (__attribute__((address_space(3))) u32*)l, 16, 0, 0);
}

// d2 in (128, 384); monotone clamped encode, units of 1/256.
__device__ inline u16 enc_d2(float d2) {
  int e = (int)((d2 - 128.f) * 256.f);
  e = e < 0 ? 0 : e;
  e = e > 65535 ? 65535 : e;
  return (u16)e;
}

// ---------------- prep: f16 planes + row norms (x and emb) ----------------
__global__ __launch_bounds__(256) void vq_prep(const float* __restrict__ x,
                                               const float* __restrict__ emb,
                                               u16* __restrict__ xf, u16* __restrict__ ef,
                                               float* __restrict__ xnorm,
                                               float* __restrict__ enorm) {
  int gid = blockIdx.x * blockDim.x + threadIdx.x;
  int r = gid >> 6, lane = gid & 63;
  const float* src;
  u16* pf;
  float* pn;
  if (r < NN) {
    src = x + (size_t)r * DD;
    pf = xf + (size_t)r * DD;
    pn = xnorm + r;
  } else {
    int rr = r - NN;
    if (rr >= KK) return;
    src = emb + (size_t)rr * DD;
    pf = ef + (size_t)rr * DD;
    pn = enorm + rr;
  }
  float4 v = ((const float4*)src)[lane];
  ushort4 h;
  _Float16 t0 = (_Float16)v.x; h.x = *(const u16*)&t0;
  _Float16 t1 = (_Float16)v.y; h.y = *(const u16*)&t1;
  _Float16 t2 = (_Float16)v.z; h.z = *(const u16*)&t2;
  _Float16 t3 = (_Float16)v.w; h.w = *(const u16*)&t3;
  ((ushort4*)pf)[lane] = h;
  float s = v.x * v.x + v.y * v.y + v.z * v.z + v.w * v.w;
#pragma unroll
  for (int off = 32; off > 0; off >>= 1) s += __shfl_down(s, off, 64);
  if (lane == 0) *pn = s;
}

// ---------------- blocked transpose: embT4[d/4][k] = emb[k][4d..4d+3] ----------------
__global__ __launch_bounds__(256) void vq_trans(const float* __restrict__ emb,
                                                float4* __restrict__ embT4) {
  __shared__ float t[64][65];
  const int r0 = blockIdx.x * 64;   // KK/64 = 128
  const int d0 = blockIdx.y * 64;   // DD/64 = 4
  const int tid = threadIdx.x;
#pragma unroll
  for (int i = 0; i < 4; ++i) {
    int flat = i * 256 + tid;
    int rr = flat >> 4, c4 = flat & 15;
    float4 v = *(const float4*)(emb + (size_t)(r0 + rr) * DD + d0 + c4 * 4);
    t[rr][c4 * 4 + 0] = v.x; t[rr][c4 * 4 + 1] = v.y;
    t[rr][c4 * 4 + 2] = v.z; t[rr][c4 * 4 + 3] = v.w;
  }
  __syncthreads();
#pragma unroll
  for (int i = 0; i < 4; ++i) {
    int flat = i * 256 + tid;
    int k = flat & 63, jb = flat >> 6;   // jb 0..15
    float4 v = {t[k][jb * 4 + 0], t[k][jb * 4 + 1], t[k][jb * 4 + 2], t[k][jb * 4 + 3]};
    embT4[(size_t)(d0 / 4 + jb) * KK + r0 + k] = v;
  }
}

// ---------------- main MFMA screening kernel (unchanged from validated R4) ----------------
__global__ __launch_bounds__(256, 4) void vq_mfma(const u16* __restrict__ xf,
                                                  const u16* __restrict__ ef,
                                                  const float* __restrict__ xnorm,
                                                  const float* __restrict__ enorm,
                                                  u16* __restrict__ partial) {
  __shared__ u16 lds[2][1024][8];
  const int tid = threadIdx.x;
  const int lane = tid & 63;
  const int wid = tid >> 6;
  const int wr = wid >> 1, wc = wid & 1;
  const int r0 = blockIdx.x * BM;
  const int cbase = blockIdx.y * (KK / CSPLIT);
  const int u_ = lane >> 4, t_ = lane & 15;

  f32x4 acc[4][4];
#pragma unroll
  for (int i = 0; i < 4; ++i)
#pragma unroll
    for (int j = 0; j < 4; ++j) acc[i][j] = (f32x4){0.f, 0.f, 0.f, 0.f};

  auto STAGE = [&](int buf, int ct, int kc) {
    const int c0 = cbase + ct * BN;
#pragma unroll
    for (int i = 0; i < 4; ++i) {
      const int f = wid * 256 + i * 64 + lane;
      const int plane = f >> 9, kgrp = (f >> 7) & 3, row = f & 127;
      const u16* src = plane ? (ef + (size_t)(c0 + row) * DD)
                             : (xf + (size_t)(r0 + row) * DD);
      gload16(src + kc * 32 + kgrp * 8, &lds[buf][f][0]);
    }
  };

  STAGE(0, 0, 0);
  __syncthreads();
  int cur = 0;

  for (int step = 0; step < 128; ++step) {
    const int ct = step >> 3, kc = step & 7;
    if (step + 1 < 128) STAGE(cur ^ 1, (step + 1) >> 3, (step + 1) & 7);

    f16x8 bh[4];
#pragma unroll
    for (int nf = 0; nf < 4; ++nf)
      bh[nf] = *(const f16x8*)&lds[cur][512 + u_ * 128 + wc * 64 + nf * 16 + t_][0];
#pragma unroll
    for (int mf = 0; mf < 4; ++mf) {
      f16x8 ah = *(const f16x8*)&lds[cur][u_ * 128 + wr * 64 + mf * 16 + t_][0];
#pragma unroll
      for (int nf = 0; nf < 4; ++nf)
        acc[mf][nf] = __builtin_amdgcn_mfma_f32_16x16x32_f16(ah, bh[nf], acc[mf][nf], 0, 0, 0);
    }

    if (kc == 7) {
      const int c0 = cbase + ct * BN;
      const int g = (c0 + wc * 64) >> 6;
      float en[4];
#pragma unroll
      for (int nf = 0; nf < 4; ++nf) en[nf] = enorm[c0 + wc * 64 + nf * 16 + t_];
#pragma unroll
      for (int mf = 0; mf < 4; ++mf) {
        const int rowb = r0 + wr * 64 + mf * 16 + u_ * 4;
#pragma unroll
        for (int q = 0; q < 4; ++q) {
          const float xx = xnorm[rowb + q];
          float d0 = fmaf(-2.f, acc[mf][0][q], xx) + en[0];
          float d1 = fmaf(-2.f, acc[mf][1][q], xx) + en[1];
          float d2 = fmaf(-2.f, acc[mf][2][q], xx) + en[2];
          float d3 = fmaf(-2.f, acc[mf][3][q], xx) + en[3];
          float gm = fminf(fminf(d0, d1), fminf(d2, d3));
#pragma unroll
          for (int off = 1; off < 16; off <<= 1) gm = fminf(gm, __shfl_xor(gm, off, 64));
          if (t_ == 0) partial[(size_t)(rowb + q) * NG + g] = enc_d2(gm);
        }
#pragma unroll
        for (int nf = 0; nf < 4; ++nf) acc[mf][nf] = (f32x4){0.f, 0.f, 0.f, 0.f};
      }
    }
    __syncthreads();
    cur ^= 1;
  }
}

// ---------------- fused post: select + exact rescore (coalesced via embT4) ----------------
__global__ __launch_bounds__(256) void vq_post(const float* __restrict__ x,
                                               const float* __restrict__ emb,
                                               const float4* __restrict__ embT4,
                                               const float* __restrict__ xnorm,
                                               const float* __restrict__ enorm,
                                               const u16* __restrict__ partial,
                                               float* __restrict__ losspart,
                                               float* __restrict__ out) {
  __shared__ float lred[4];
  const int tid = threadIdx.x, lane = tid & 63, wid = tid >> 6;
  const int row = blockIdx.x * 4 + wid;

  // coalesced groupmin load: 128 u16 per row = 1 u32 per lane
  const u32 wbuf = ((const u32*)(partial + (size_t)row * NG))[lane];
  int mymin = min((int)(wbuf & 0xFFFFu), (int)(wbuf >> 16));
#pragma unroll
  for (int off = 1; off < 64; off <<= 1) mymin = min(mymin, __shfl_xor(mymin, off, 64));
  const int thr = mymin + 1;  // provably-safe: 2*eps_f16 < 1 enc unit

  u32 mask = 0;
  if ((int)(wbuf & 0xFFFFu) <= thr) mask |= 1u;
  if ((int)(wbuf >> 16) <= thr) mask |= 2u;

  const float xx = xnorm[row];
  const float* xrow = x + (size_t)row * DD;
  u64 best = ~0ull;
  u64 lanesw = __ballot(mask != 0);
  while (lanesw) {
    int src = __ffsll((unsigned long long)lanesw) - 1;
    lanesw &= lanesw - 1;
    u32 lm = __shfl(mask, src, 64);
    while (lm) {
      int s = __ffs(lm) - 1;
      lm &= lm - 1;
      const int g = src * 2 + s;
      const int code = (g << 6) + lane;  // lane owns one code; reads now coalesced
      float a = 0.f;
      // identical ascending-d sequential fmaf chain (validated); only the
      // embedding load addresses changed (embT4 = blocked transpose).
#pragma unroll 8
      for (int db = 0; db < 64; ++db) {
        float4 xv = *(const float4*)(xrow + db * 4);          // broadcast
        float4 ev = embT4[(size_t)db * KK + code];            // 1KB coalesced/wave
        a = fmaf(xv.x, ev.x, a);
        a = fmaf(xv.y, ev.y, a);
        a = fmaf(xv.z, ev.z, a);
        a = fmaf(xv.w, ev.w, a);
      }
      float d2 = fmaf(-2.f, a, xx) + enorm[code];
      u64 pk = ((u64)__float_as_uint(d2) << 32) | (u32)code;
      if (pk < best) best = pk;
    }
  }
#pragma unroll
  for (int off = 1; off < 64; off <<= 1) {
    u64 o = __shfl_xor(best, off, 64);
    if (o < best) best = o;
  }
  const int bi = (int)(u32)(best & 0xFFFFFFFFull);

  if (lane == 0) out[(size_t)NN * DD + 2 + row] = (float)bi;
  float4 qv = ((const float4*)(emb + (size_t)bi * DD))[lane];
  float4 xv = ((const float4*)xrow)[lane];
  float4 st;
  st.x = xv.x + (qv.x - xv.x);
  st.y = xv.y + (qv.y - xv.y);
  st.z = xv.z + (qv.z - xv.z);
  st.w = xv.w + (qv.w - xv.w);
  ((float4*)(out + (size_t)row * DD))[lane] = st;

  float dx = xv.x - qv.x, dy = xv.y - qv.y, dz = xv.z - qv.z, dw = xv.w - qv.w;
  float s2 = dx * dx + dy * dy + dz * dz + dw * dw;
#pragma unroll
  for (int off = 32; off > 0; off >>= 1) s2 += __shfl_down(s2, off, 64);
  if (lane == 0) lred[wid] = s2;
  __syncthreads();
  if (tid == 0) losspart[blockIdx.x] = lred[0] + lred[1] + lred[2] + lred[3];
}

__global__ __launch_bounds__(256) void vq_finalize(const float* __restrict__ losspart,
                                                   float* __restrict__ out) {
  __shared__ float l[256];
  float s = 0.f;
  for (int i = threadIdx.x; i < NN / 4; i += 256) s += losspart[i];
  l[threadIdx.x] = s;
  __syncthreads();
  for (int o = 128; o > 0; o >>= 1) {
    if (threadIdx.x < o) l[threadIdx.x] += l[threadIdx.x + o];
    __syncthreads();
  }
  if (threadIdx.x == 0) {
    float loss = l[0] / (float)((size_t)NN * DD);
    out[(size_t)NN * DD] = loss;
    out[(size_t)NN * DD + 1] = loss;
  }
}

// ---------------- fallback path (round-1 validated, f32 VALU) ----------------
__global__ __launch_bounds__(256) void fb_norms(const float* __restrict__ x,
                                                const float* __restrict__ emb,
                                                float* __restrict__ ws) {
  int gid = blockIdx.x * blockDim.x + threadIdx.x;
  int wave = gid >> 6, lane = gid & 63;
  const float* src;
  float* dst;
  if (wave < KK) { src = emb + (size_t)wave * DD; dst = ws + WSF_ENORM + wave; }
  else {
    int r = wave - KK;
    if (r >= NN) return;
    src = x + (size_t)r * DD; dst = ws + WSF_XNORM + r;
  }
  float4 v = ((const float4*)src)[lane];
  float s = v.x * v.x + v.y * v.y + v.z * v.z + v.w * v.w;
#pragma unroll
  for (int off = 32; off > 0; off >>= 1) s += __shfl_down(s, off, 64);
  if (lane == 0) *dst = s;
}

__global__ __launch_bounds__(256) void fb_argmin(const float* __restrict__ x,
                                                 const float* __restrict__ emb,
                                                 float* __restrict__ ws) {
  const float* enorm = ws + WSF_ENORM;
  const float* xnorm = ws + WSF_XNORM;
  float* candv = ws + WSF_CANDV;
  int* candi = (int*)(ws + WSF_CANDI);
  __shared__ float As[32][BM + 4];
  __shared__ float Bs[32][BN + 4];
  const int tid = threadIdx.x;
  const int tr = tid >> 4, tc = tid & 15;
  const int r0 = blockIdx.x * BM;
  const int split = blockIdx.y;
  const int cb = split * (KK / FCSPLIT);
  float xr[8];
  {
    const float4* p = (const float4*)(xnorm + r0 + tr * 8);
    float4 a = p[0], b = p[1];
    xr[0] = a.x; xr[1] = a.y; xr[2] = a.z; xr[3] = a.w;
    xr[4] = b.x; xr[5] = b.y; xr[6] = b.z; xr[7] = b.w;
  }
  float bestv[8];
  int besti[8];
#pragma unroll
  for (int i = 0; i < 8; i++) { bestv[i] = FLT_MAX; besti[i] = 0; }
  for (int ct = 0; ct < (KK / FCSPLIT) / BN; ++ct) {
    const int c0 = cb + ct * BN;
    float acc[8][8];
#pragma unroll
    for (int i = 0; i < 8; i++)
#pragma unroll
      for (int j = 0; j < 8; j++) acc[i][j] = 0.f;
    for (int kc = 0; kc < DD; kc += 32) {
      __syncthreads();
      const int rrow = tid >> 3, dg = tid & 7;
#pragma unroll
      for (int p = 0; p < 4; ++p) {
        int rw = p * 32 + rrow;
        float4 av = ((const float4*)(x + (size_t)(r0 + rw) * DD + kc))[dg];
        float4 bv = ((const float4*)(emb + (size_t)(c0 + rw) * DD + kc))[dg];
        As[dg * 4 + 0][rw] = av.x; As[dg * 4 + 1][rw] = av.y;
        As[dg * 4 + 2][rw] = av.z; As[dg * 4 + 3][rw] = av.w;
        Bs[dg * 4 + 0][rw] = bv.x; Bs[dg * 4 + 1][rw] = bv.y;
        Bs[dg * 4 + 2][rw] = bv.z; Bs[dg * 4 + 3][rw] = bv.w;
      }
      __syncthreads();
#pragma unroll 4
      for (int kk = 0; kk < 32; ++kk) {
        float4 a0 = *(const float4*)&As[kk][tr * 8];
        float4 a1 = *(const float4*)&As[kk][tr * 8 + 4];
        float4 b0 = *(const float4*)&Bs[kk][tc * 8];
        float4 b1 = *(const float4*)&Bs[kk][tc * 8 + 4];
        float a[8] = {a0.x, a0.y, a0.z, a0.w, a1.x, a1.y, a1.z, a1.w};
        float b[8] = {b0.x, b0.y, b0.z, b0.w, b1.x, b1.y, b1.z, b1.w};
#pragma unroll
        for (int i = 0; i < 8; i++)
#pragma unroll
          for (int j = 0; j < 8; j++) acc[i][j] = fmaf(a[i], b[j], acc[i][j]);
      }
    }
    float en[8];
    {
      const float4* p = (const float4*)(enorm + c0 + tc * 8);
      float4 a = p[0], b = p[1];
      en[0] = a.x; en[1] = a.y; en[2] = a.z; en[3] = a.w;
      en[4] = b.x; en[5] = b.y; en[6] = b.z; en[7] = b.w;
    }
#pragma unroll
    for (int i = 0; i < 8; i++)
#pragma unroll
      for (int j = 0; j < 8; j++) {
        float t = fmaf(-2.f, acc[i][j], xr[i]);
        float d2 = t + en[j];
        int code = c0 + tc * 8 + j;
        if (d2 < bestv[i]) { bestv[i] = d2; besti[i] = code; }
      }
  }
#pragma unroll
  for (int i = 0; i < 8; i++) {
    float v = bestv[i];
    int bi = besti[i];
#pragma unroll
    for (int off = 1; off < 16; off <<= 1) {
      float v2 = __shfl_xor(v, off, 64);
      int i2 = __shfl_xor(bi, off, 64);
      if (v2 < v || (v2 == v && i2 < bi)) { v = v2; bi = i2; }
    }
    if (tc == 0) {
      int row = r0 + tr * 8 + i;
      candv[row * FCSPLIT + split] = v;
      candi[row * FCSPLIT + split] = bi;
    }
  }
}

__global__ __launch_bounds__(256) void fb_gather(const float* __restrict__ x,
                                                 const float* __restrict__ emb,
                                                 float* __restrict__ ws,
                                                 float* __restrict__ out) {
  const float* candv = ws + WSF_CANDV;
  const int* candi = (const int*)(ws + WSF_CANDI);
  float* loss_acc = ws + WSF_LOSS;
  int gid = blockIdx.x * blockDim.x + threadIdx.x;
  int row = gid >> 6, lane = gid & 63;
  if (row >= NN) return;
  float bv = candv[row * FCSPLIT];
  int bi = candi[row * FCSPLIT];
#pragma unroll
  for (int s = 1; s < FCSPLIT; s++) {
    float v = candv[row * FCSPLIT + s];
    int ii = candi[row * FCSPLIT + s];
    if (v < bv || (v == bv && ii < bi)) { bv = v; bi = ii; }
  }
  if (lane == 0) out[(size_t)NN * DD + 2 + row] = (float)bi;
  float4 qv = ((const float4*)(emb + (size_t)bi * DD))[lane];
  float4 xv = ((const float4*)(x + (size_t)row * DD))[lane];
  float4 st;
  st.x = xv.x + (qv.x - xv.x);
  st.y = xv.y + (qv.y - xv.y);
  st.z = xv.z + (qv.z - xv.z);
  st.w = xv.w + (qv.w - xv.w);
  ((float4*)(out + (size_t)row * DD))[lane] = st;
  float dx = xv.x - qv.x, dy = xv.y - qv.y, dz = xv.z - qv.z, dw = xv.w - qv.w;
  float s2 = dx * dx + dy * dy + dz * dz + dw * dw;
#pragma unroll
  for (int off = 32; off > 0; off >>= 1) s2 += __shfl_down(s2, off, 64);
  if (lane == 0) atomicAdd(loss_acc, s2);
}

__global__ void fb_finalize(const float* __restrict__ ws, float* __restrict__ out) {
  float loss = ws[WSF_LOSS] / (float)((size_t)NN * DD);
  out[(size_t)NN * DD] = loss;
  out[(size_t)NN * DD + 1] = loss;
}

// ---------------- launch ----------------
extern "C" void kernel_launch(void* const* d_in, const int* in_sizes, int n_in,
                              void* d_out, int out_size, void* d_ws, size_t ws_size,
                              hipStream_t stream) {
  const float* x = (const float*)d_in[0];
  const float* emb = (const float*)d_in[1];
  float* out = (float*)d_out;
  char* ws = (char*)d_ws;

  if (ws_size >= WB_NEED) {
    float* enorm = (float*)(ws + WB_ENORM);
    float* xnorm = (float*)(ws + WB_XNORM);
    u16* ef = (u16*)(ws + WB_EF);
    float4* embT4 = (float4*)(ws + WB_ET);
    float* losspart = (float*)(ws + WB_LOSSP);
    u16* partial = (u16*)(ws + WB_PARTIAL);
    // x f16 plane lives in d_out's quantized region (16 MB of 33.7 MB);
    // written by prep, read by mfma, overwritten by post — stream-ordered.
    u16* xf = (u16*)out;

    vq_prep<<<(NN + KK) / 4, 256, 0, stream>>>(x, emb, xf, ef, xnorm, enorm);
    vq_trans<<<dim3(KK / 64, DD / 64), 256, 0, stream>>>(emb, embT4);
    vq_mfma<<<dim3(NN / BM, CSPLIT), 256, 0, stream>>>(xf, ef, xnorm, enorm, partial);
    vq_post<<<NN / 4, 256, 0, stream>>>(x, emb, embT4, xnorm, enorm, partial, losspart, out);
    vq_finalize<<<1, 256, 0, stream>>>(losspart, out);
  } else {
    float* wsf = (float*)d_ws;
    hipMemsetAsync(ws + (size_t)WSF_LOSS * 4, 0, 4, stream);
    fb_norms<<<((KK + NN) * 64) / 256, 256, 0, stream>>>(x, emb, wsf);
    fb_argmin<<<dim3(NN / BM, FCSPLIT), 256, 0, stream>>>(x, emb, wsf);
    fb_gather<<<(NN * 64) / 256, 256, 0, stream>>>(x, emb, wsf, out);
    fb_finalize<<<1, 1, 0, stream>>>(wsf, out);
  }
}